// Round 2
// baseline (1411.674 us; speedup 1.0000x reference)
//
#include <hip/hip_runtime.h>
#include <cstdint>

// ---- problem constants ----
#define B_    4
#define N_    2048
#define D_    1024
#define DC_   256
#define E_    8
#define NE    7          // routed experts addressable by router (E-1)
#define HID_  4096
#define T_    8192       // B*N
#define CAP_  2560       // int(1.25*2*T/E)
#define TP_   16384      // T*TOPK

typedef unsigned short us;

__device__ __forceinline__ float b2f(us h) {
    unsigned u = ((unsigned)h) << 16; float f; __builtin_memcpy(&f, &u, 4); return f;
}
__device__ __forceinline__ us f2b(float f) {
    unsigned u; __builtin_memcpy(&u, &f, 4);
    unsigned r = (u + 0x7fffu + ((u >> 16) & 1u)) >> 16;   // RNE
    return (us)r;
}

using short8 = __attribute__((ext_vector_type(8))) short;
using f32x4  = __attribute__((ext_vector_type(4))) float;

typedef __attribute__((address_space(1))) void GASV;
typedef __attribute__((address_space(3))) void LASV;
__device__ __forceinline__ void gld16(const void* g, void* l) {
    // async global->LDS, 16B/lane, LDS dest = wave-uniform base + lane*16
    __builtin_amdgcn_global_load_lds((GASV*)g, (LASV*)l, 16, 0, 0);
}

// =====================================================================
// 0. sentinel (debug channel: ws too small -> absmax ~12345 next round)
// =====================================================================
__global__ void sentinel_kernel(float* out) { out[0] = 12345.0f; }

// =====================================================================
// 1. Fused router + LayerNorm: one wave per token.
// =====================================================================
__global__ __launch_bounds__(256) void router_ln_kernel(
    const float* __restrict__ x, const float* __restrict__ Wg,
    int* __restrict__ flat_e, float* __restrict__ flat_w, us* __restrict__ lnb)
{
    __shared__ float sWg[D_ * NE];
    for (int i = threadIdx.x; i < D_ * NE; i += 256) sWg[i] = Wg[i];
    __syncthreads();
    const int wave = threadIdx.x >> 6, lane = threadIdx.x & 63;
    const int t = blockIdx.x * 4 + wave;
    const float* xr = x + (size_t)t * D_;

    float v[16];
#pragma unroll
    for (int q = 0; q < 4; q++) {
        float4 f = *(const float4*)(xr + lane * 16 + q * 4);
        v[q*4+0] = f.x; v[q*4+1] = f.y; v[q*4+2] = f.z; v[q*4+3] = f.w;
    }
    float s7[NE] = {0,0,0,0,0,0,0};
    float sum = 0.f, sq = 0.f;
#pragma unroll
    for (int u = 0; u < 16; u++) {
        float xv = v[u]; int d = lane * 16 + u;
        sum += xv; sq += xv * xv;
#pragma unroll
        for (int j = 0; j < NE; j++) s7[j] += xv * sWg[d * NE + j];
    }
#pragma unroll
    for (int off = 32; off; off >>= 1) {
        sum += __shfl_xor(sum, off, 64);
        sq  += __shfl_xor(sq,  off, 64);
#pragma unroll
        for (int j = 0; j < NE; j++) s7[j] += __shfl_xor(s7[j], off, 64);
    }
    const float mu  = sum * (1.f / D_);
    const float var = sq * (1.f / D_) - mu * mu;
    const float rs  = rsqrtf(var + 1e-5f);

    us* lr = lnb + (size_t)t * D_ + lane * 16;
#pragma unroll
    for (int half = 0; half < 2; half++) {
        union { us h[8]; uint4 u4; } p;
#pragma unroll
        for (int u = 0; u < 8; u++) p.h[u] = f2b((v[half*8+u] - mu) * rs);
        *(uint4*)(lr + half * 8) = p.u4;
    }
    if (lane == 0) {
        float m = s7[0];
#pragma unroll
        for (int j = 1; j < NE; j++) m = fmaxf(m, s7[j]);
        float ex[NE];
#pragma unroll
        for (int j = 0; j < NE; j++) ex[j] = __expf(s7[j] - m);
        int i1 = 0;
#pragma unroll
        for (int j = 1; j < NE; j++) if (ex[j] > ex[i1]) i1 = j;
        int i2 = (i1 == 0) ? 1 : 0;
#pragma unroll
        for (int j = 0; j < NE; j++) if (j != i1 && ex[j] > ex[i2]) i2 = j;
        float wA = ex[i1], wB = ex[i2], iw = 1.f / (wA + wB);
        flat_e[t*2]   = i1; flat_e[t*2+1] = i2;
        flat_w[t*2]   = wA * iw; flat_w[t*2+1] = wB * iw;
    }
}

// =====================================================================
// 2. Binning: stable counting sort by expert (single block).
// =====================================================================
__global__ __launch_bounds__(256) void binning_kernel(
    const int* __restrict__ flat_e, int* __restrict__ bin_idx,
    int* __restrict__ dest_slot, int* __restrict__ n_e)
{
    __shared__ int hist[NE][257];
    const int t = threadIdx.x;
    const int base = t * 64;           // 256 threads * 64 = 16384 pairs
    int cnt[NE] = {0,0,0,0,0,0,0};
    for (int i = 0; i < 64; i++) {
        int fe = flat_e[base + i];
#pragma unroll
        for (int e = 0; e < NE; e++) cnt[e] += (fe == e);
    }
#pragma unroll
    for (int e = 0; e < NE; e++) hist[e][t] = cnt[e];
    __syncthreads();
    if (t < NE) {
        int run = 0;
        for (int i = 0; i < 256; i++) { int c = hist[t][i]; hist[t][i] = run; run += c; }
        n_e[t] = run < CAP_ ? run : CAP_;
    }
    __syncthreads();
    for (int i = t; i < NE * CAP_; i += 256) bin_idx[i] = -1;
    __syncthreads();
    int ofs[NE];
#pragma unroll
    for (int e = 0; e < NE; e++) ofs[e] = hist[e][t];
    for (int i = 0; i < 64; i++) {
        int idx = base + i;
        int fe = flat_e[idx];
        int r = 0;
#pragma unroll
        for (int e = 0; e < NE; e++) if (fe == e) r = ofs[e]++;
        int slot = (r < CAP_) ? (fe * CAP_ + r) : -1;
        dest_slot[idx] = slot;
        if (slot >= 0) bin_idx[slot] = idx;
    }
}

// =====================================================================
// 3. fp32 -> bf16 elementwise convert (cond)
// =====================================================================
__global__ void cvt_bf16_kernel(const float* __restrict__ in, us* __restrict__ out, long n) {
    long i = ((long)blockIdx.x * 256 + threadIdx.x) * 4;
    if (i >= n) return;
    float4 f = *(const float4*)(in + i);
    union { us h[4]; uint2 u; } p;
    p.h[0] = f2b(f.x); p.h[1] = f2b(f.y); p.h[2] = f2b(f.z); p.h[3] = f2b(f.w);
    *(uint2*)(out + i) = p.u;
}

// =====================================================================
// 4. Weight convert + transpose: W[K,N] fp32 -> WT[N,K] bf16
// =====================================================================
__global__ __launch_bounds__(256) void convT_kernel(
    const float* __restrict__ W, us* __restrict__ WT, int K, int N, long sW, long sWT)
{
    const float* Wp = W + (size_t)blockIdx.z * sW;
    us* WTp = WT + (size_t)blockIdx.z * sWT;
    __shared__ us tl[32][33];
    const int k0 = blockIdx.y * 32, n0 = blockIdx.x * 32;
    const int tx = threadIdx.x & 31, ty = threadIdx.x >> 5;
#pragma unroll
    for (int r = ty; r < 32; r += 8)
        tl[r][tx] = f2b(Wp[(size_t)(k0 + r) * N + n0 + tx]);
    __syncthreads();
#pragma unroll
    for (int r = ty; r < 32; r += 8)
        WTp[(size_t)(n0 + r) * K + k0 + tx] = tl[tx][r];
}

// =====================================================================
// 5. Gather cond rows (bf16) into bin order; invalid slots -> zeros
// =====================================================================
__global__ __launch_bounds__(256) void gather_cond_kernel(
    const us* __restrict__ cond_bf, const int* __restrict__ bin_idx, us* __restrict__ cond_g)
{
    const int row = blockIdx.x * 4 + (threadIdx.x >> 6);
    const int lane = threadIdx.x & 63;
    const int pi = bin_idx[row];
    uint2 val = {0u, 0u};
    if (pi >= 0) val = *(const uint2*)(cond_bf + (size_t)(pi >> 1) * DC_ + lane * 4);
    *(uint2*)(cond_g + (size_t)row * DC_ + lane * 4) = val;
}

// =====================================================================
// 6. GEMM: C[M,N] = A[M,K](bf16) @ BT[N,K]^T + bias. 128x128 tiles,
//    mfma_f32_16x16x32_bf16, global_load_lds(16B). epi:
//      0 = ada split (shift/scale/gate bf16)
//      1 = gelu -> bf16
//      2 = plain -> bf16
//      3 = shared-out: fp32 d_out = val*gate*mask/3
// =====================================================================
struct GArgs {
    const us* A; const us* BT; const float* bias;
    us* out0; us* out1; us* out2;
    const us* gateP; const float* maskP; float* outF;
    int M, N, K, ldOut;
    long sA_e, sBT_e, sBias_e, sOut_e;
    const int* n_e;
    int epi;
};

__global__ __launch_bounds__(256) void gemm_bt(GArgs g) {
    const int e = blockIdx.z;
    int rows = g.M;
    if (g.n_e) { int ne = g.n_e[e]; if (ne < rows) rows = ne; }
    const int mbase = blockIdx.y * 128;
    if (mbase >= rows) return;                 // block-uniform early exit
    const int nbase = blockIdx.x * 128;
    const us* A  = g.A  + (size_t)e * g.sA_e;
    const us* BT = g.BT + (size_t)e * g.sBT_e;
    const int K = g.K;

    __shared__ __align__(16) us sA[128 * 32];
    __shared__ __align__(16) us sB[128 * 32];

    const int tid = threadIdx.x;
    const int wave = tid >> 6, lane = tid & 63;
    const int wm = wave >> 1, wn = wave & 1;
    const int lrow = lane & 15, lq = lane >> 4;
    const int r0 = lane >> 2;                  // row within 16-row staging group
    const int cb = (lane & 3) * 8;             // k-element offset (8 bf16 = 16B)

    const size_t aOff0 = (size_t)(mbase + wave * 16 + r0) * K + cb;
    const size_t aOff1 = aOff0 + (size_t)64 * K;
    const size_t bOff0 = (size_t)(nbase + wave * 16 + r0) * K + cb;
    const size_t bOff1 = bOff0 + (size_t)64 * K;

    f32x4 acc[4][4];
#pragma unroll
    for (int i = 0; i < 4; i++)
#pragma unroll
        for (int j = 0; j < 4; j++) acc[i][j] = (f32x4)0.0f;

    for (int k0 = 0; k0 < K; k0 += 32) {
        gld16(A + aOff0 + k0, &sA[wave * 512]);
        gld16(A + aOff1 + k0, &sA[(wave + 4) * 512]);
        gld16(BT + bOff0 + k0, &sB[wave * 512]);
        gld16(BT + bOff1 + k0, &sB[(wave + 4) * 512]);
        __syncthreads();
        short8 af[4], bf[4];
#pragma unroll
        for (int i = 0; i < 4; i++) {
            af[i] = *(const short8*)&sA[(wm * 64 + i * 16 + lrow) * 32 + lq * 8];
            bf[i] = *(const short8*)&sB[(wn * 64 + i * 16 + lrow) * 32 + lq * 8];
        }
#pragma unroll
        for (int i = 0; i < 4; i++)
#pragma unroll
            for (int j = 0; j < 4; j++)
                acc[i][j] = __builtin_amdgcn_mfma_f32_16x16x32_bf16(af[i], bf[j], acc[i][j], 0, 0, 0);
        __syncthreads();
    }

    const float* bias = g.bias + (size_t)e * g.sBias_e;
    float bv[4];
#pragma unroll
    for (int j = 0; j < 4; j++) bv[j] = bias[nbase + wn * 64 + j * 16 + lrow];

    if (g.epi == 0) {
        const int seg = nbase >> 10;           // 128-tile never straddles 1024
        us* ob = (seg == 0) ? g.out0 : (seg == 1) ? g.out1 : g.out2;
        ob += (size_t)e * g.sOut_e;
        const int coll = nbase - (seg << 10) + wn * 64 + lrow;
#pragma unroll
        for (int i = 0; i < 4; i++)
#pragma unroll
            for (int r = 0; r < 4; r++) {
                int row = mbase + wm * 64 + i * 16 + lq * 4 + r;
#pragma unroll
                for (int j = 0; j < 4; j++)
                    ob[(size_t)row * 1024 + coll + j * 16] = f2b(acc[i][j][r] + bv[j]);
            }
    } else if (g.epi == 1) {
        us* ob = g.out0 + (size_t)e * g.sOut_e;
#pragma unroll
        for (int i = 0; i < 4; i++)
#pragma unroll
            for (int r = 0; r < 4; r++) {
                int row = mbase + wm * 64 + i * 16 + lq * 4 + r;
#pragma unroll
                for (int j = 0; j < 4; j++) {
                    float v = acc[i][j][r] + bv[j];
                    // jax.nn.gelu approximate=True (tanh form)
                    float u = 0.7978845608028654f * (v + 0.044715f * v * v * v);
                    float exu = __expf(2.f * u);
                    float th = 1.f - 2.f / (exu + 1.f);
                    ob[(size_t)row * g.ldOut + nbase + wn * 64 + j * 16 + lrow] = f2b(0.5f * v * (1.f + th));
                }
            }
    } else if (g.epi == 2) {
        us* ob = g.out0 + (size_t)e * g.sOut_e;
#pragma unroll
        for (int i = 0; i < 4; i++)
#pragma unroll
            for (int r = 0; r < 4; r++) {
                int row = mbase + wm * 64 + i * 16 + lq * 4 + r;
#pragma unroll
                for (int j = 0; j < 4; j++)
                    ob[(size_t)row * g.ldOut + nbase + wn * 64 + j * 16 + lrow] = f2b(acc[i][j][r] + bv[j]);
            }
    } else {
        // epi 3: fused shared-expert output. out = val * gate * mask / 3 (fp32)
        float* ob = g.outF;
#pragma unroll
        for (int i = 0; i < 4; i++)
#pragma unroll
            for (int r = 0; r < 4; r++) {
                int row = mbase + wm * 64 + i * 16 + lq * 4 + r;
                float mrow = g.maskP[row] * (1.f / 3.f);
#pragma unroll
                for (int j = 0; j < 4; j++) {
                    int col = nbase + wn * 64 + j * 16 + lrow;
                    float v = acc[i][j][r] + bv[j];
                    ob[(size_t)row * 1024 + col] = v * b2f(g.gateP[(size_t)row * 1024 + col]) * mrow;
                }
            }
    }
}

// =====================================================================
// 7. Modulation: hmod = ln*(1+scale)+shift  (bf16 in/out)
// =====================================================================
__global__ void modulate_s_kernel(const us* __restrict__ lnb, const us* __restrict__ shift,
                                  const us* __restrict__ scale, us* __restrict__ hmod)
{
    size_t i = ((size_t)blockIdx.x * 256 + threadIdx.x) * 4;
    uint2 l  = *(const uint2*)(lnb + i);
    uint2 sh = *(const uint2*)(shift + i);
    uint2 sc = *(const uint2*)(scale + i);
    const us* lp = (const us*)&l; const us* shp = (const us*)&sh; const us* scp = (const us*)&sc;
    union { us h[4]; uint2 u; } o;
#pragma unroll
    for (int u = 0; u < 4; u++)
        o.h[u] = f2b(b2f(lp[u]) * (1.f + b2f(scp[u])) + b2f(shp[u]));
    *(uint2*)(hmod + i) = o.u;
}

__global__ void modulate_g_kernel(const us* __restrict__ lnb, const us* __restrict__ shift_g,
                                  const us* __restrict__ scale_g, const int* __restrict__ bin_idx,
                                  us* __restrict__ hmod_g)
{
    const int slot = blockIdx.x;
    const int d = threadIdx.x * 4;
    const int pi = bin_idx[slot];
    float lv[4] = {0.f, 0.f, 0.f, 0.f};
    if (pi >= 0) {
        uint2 l = *(const uint2*)(lnb + (size_t)(pi >> 1) * D_ + d);
        const us* lp = (const us*)&l;
#pragma unroll
        for (int u = 0; u < 4; u++) lv[u] = b2f(lp[u]);
    }
    const size_t off = (size_t)slot * 1024 + d;
    uint2 sh = *(const uint2*)(shift_g + off);
    uint2 sc = *(const uint2*)(scale_g + off);
    const us* shp = (const us*)&sh; const us* scp = (const us*)&sc;
    union { us h[4]; uint2 u; } o;
#pragma unroll
    for (int u = 0; u < 4; u++)
        o.h[u] = f2b(lv[u] * (1.f + b2f(scp[u])) + b2f(shp[u]));
    *(uint2*)(hmod_g + off) = o.u;
}

// =====================================================================
// 8. Combine (routed add): out[t] += mask*2/3*(w0*g0*y0 + w1*g1*y1)
//    d_out already holds the shared contribution (epi 3). Sole writer.
// =====================================================================
__global__ void combine_kernel(const us* __restrict__ y_g, const us* __restrict__ gate_g,
                               const int* __restrict__ dest_slot, const float* __restrict__ flat_w,
                               const float* __restrict__ maskp, float* __restrict__ out)
{
    const int t = blockIdx.x;
    const int d = threadIdx.x * 4;
    const size_t o = (size_t)t * D_ + d;
    float acc[4] = {0.f, 0.f, 0.f, 0.f};
    const int s0 = dest_slot[2*t], s1 = dest_slot[2*t+1];
    const float w0 = flat_w[2*t] * (2.f / 3.f), w1 = flat_w[2*t+1] * (2.f / 3.f);
    if (s0 >= 0) {
        uint2 yg = *(const uint2*)(y_g + (size_t)s0 * D_ + d);
        uint2 gg = *(const uint2*)(gate_g + (size_t)s0 * D_ + d);
        const us* yp = (const us*)&yg; const us* gp = (const us*)&gg;
#pragma unroll
        for (int u = 0; u < 4; u++) acc[u] += w0 * b2f(gp[u]) * b2f(yp[u]);
    }
    if (s1 >= 0) {
        uint2 yg = *(const uint2*)(y_g + (size_t)s1 * D_ + d);
        uint2 gg = *(const uint2*)(gate_g + (size_t)s1 * D_ + d);
        const us* yp = (const us*)&yg; const us* gp = (const us*)&gg;
#pragma unroll
        for (int u = 0; u < 4; u++) acc[u] += w1 * b2f(gp[u]) * b2f(yp[u]);
    }
    const float mk = maskp[t];
    float4 cur = *(float4*)(out + o);
    cur.x += acc[0] * mk; cur.y += acc[1] * mk;
    cur.z += acc[2] * mk; cur.w += acc[3] * mk;
    *(float4*)(out + o) = cur;
}

// =====================================================================
extern "C" void kernel_launch(void* const* d_in, const int* in_sizes, int n_in,
                              void* d_out, int out_size, void* d_ws, size_t ws_size,
                              hipStream_t stream)
{
    const float* x      = (const float*)d_in[0];
    const float* cond   = (const float*)d_in[1];
    const float* maskp  = (const float*)d_in[2];
    const float* Wg     = (const float*)d_in[3];
    const float* Wada_s = (const float*)d_in[4];
    const float* bada_s = (const float*)d_in[5];
    const float* W1_s   = (const float*)d_in[6];
    const float* b1_s   = (const float*)d_in[7];
    const float* W2_s   = (const float*)d_in[8];
    const float* b2_s   = (const float*)d_in[9];
    const float* Wada_e = (const float*)d_in[10];
    const float* bada_e = (const float*)d_in[11];
    const float* W1_e   = (const float*)d_in[12];
    const float* b1_e   = (const float*)d_in[13];
    const float* W2_e   = (const float*)d_in[14];
    const float* b2_e   = (const float*)d_in[15];
    (void)in_sizes; (void)n_in; (void)out_size;
    float* out = (float*)d_out;

    // ---------- fixed (persistent) allocations ----------
    char* p = (char*)d_ws;
    size_t off = 0;
    auto carve = [&](size_t bytes) -> void* {
        void* r = p + off; off = (off + bytes + 255) & ~(size_t)255; return r;
    };
    int*   flat_e   = (int*)carve((size_t)TP_ * 4);
    float* flat_w   = (float*)carve((size_t)TP_ * 4);
    int*   bin_idx  = (int*)carve((size_t)NE * CAP_ * 4);
    int*   dest_slot= (int*)carve((size_t)TP_ * 4);
    int*   d_ne     = (int*)carve(256);
    us*    cond_bf  = (us*)carve((size_t)T_ * DC_ * 2);          //  4.2 MB
    us*    lnb      = (us*)carve((size_t)T_ * D_ * 2);           // 16.8 MB
    us*    gate_s   = (us*)carve((size_t)T_ * D_ * 2);           // 16.8 MB
    us*    gate_g   = (us*)carve((size_t)NE * CAP_ * D_ * 2);    // 36.7 MB
    us*    y_g      = (us*)carve((size_t)NE * CAP_ * D_ * 2);    // 36.7 MB

    // ---------- scratch arena (lifetimes disjoint across phases) ----------
    char* A = p + off;
    const size_t ARENA_SZ = 103809024;   // max(phase1 92.3MB, phase2 103.8MB)
    // phase 1 (shared expert):
    us* hmod_s  = (us*)(A);                           // 16,777,216
    us* wt_s    = (us*)(A + 16777216);                //  8,388,608 (WadaT/W1T/W2T seq.)
    us* t1_s    = (us*)(A + 25165824);                // 67,108,864
    us* shift_s = (us*)(A + 25165824);                // aliases t1_s (dead before t1 write)
    us* scale_s = (us*)(A + 41943040);
    // phase 2 (routed, batches of <=3 experts):
    us* hmod_gb = (us*)(A);                           // 15,728,640
    us* wt_b    = (us*)(A + 15728640);                // 25,165,824 (WadaT/W1T/W2T seq.)
    us* t1_gb   = (us*)(A + 40894464);                // 62,914,560
    us* shift_gb= (us*)(A + 40894464);                // aliases t1_gb (dead before write)
    us* scale_gb= (us*)(A + 40894464 + 15728640);
    us* cond_gb = (us*)(A + 40894464 + 31457280);

    if (off + ARENA_SZ > ws_size) {                   // debug sentinel
        sentinel_kernel<<<1, 1, 0, stream>>>(out);
        return;
    }

    // ---------- phase 0: router + LN + binning + cond cast ----------
    router_ln_kernel<<<T_ / 4, 256, 0, stream>>>(x, Wg, flat_e, flat_w, lnb);
    binning_kernel<<<1, 256, 0, stream>>>(flat_e, bin_idx, dest_slot, d_ne);
    cvt_bf16_kernel<<<(T_ * DC_) / 1024, 256, 0, stream>>>(cond, cond_bf, (long)T_ * DC_);

    GArgs a;
    a.gateP = nullptr; a.maskP = nullptr; a.outF = nullptr;

    // ---------- phase 1: shared expert ----------
    convT_kernel<<<dim3(96, 8, 1), 256, 0, stream>>>(Wada_s, wt_s, DC_, 3072, 0, 0);
    a.A = cond_bf; a.BT = wt_s; a.bias = bada_s;
    a.out0 = shift_s; a.out1 = scale_s; a.out2 = gate_s;
    a.M = T_; a.N = 3072; a.K = DC_; a.ldOut = 1024;
    a.sA_e = 0; a.sBT_e = 0; a.sBias_e = 0; a.sOut_e = 0;
    a.n_e = nullptr; a.epi = 0;
    gemm_bt<<<dim3(24, T_ / 128, 1), 256, 0, stream>>>(a);

    modulate_s_kernel<<<(T_ * D_) / 1024, 256, 0, stream>>>(lnb, shift_s, scale_s, hmod_s);

    convT_kernel<<<dim3(128, 32, 1), 256, 0, stream>>>(W1_s, wt_s, D_, HID_, 0, 0);
    a.A = hmod_s; a.BT = wt_s; a.bias = b1_s; a.out0 = t1_s;
    a.M = T_; a.N = HID_; a.K = D_; a.ldOut = HID_; a.epi = 1;
    gemm_bt<<<dim3(HID_ / 128, T_ / 128, 1), 256, 0, stream>>>(a);

    convT_kernel<<<dim3(32, 128, 1), 256, 0, stream>>>(W2_s, wt_s, HID_, D_, 0, 0);
    a.A = t1_s; a.BT = wt_s; a.bias = b2_s; a.out0 = nullptr;
    a.gateP = gate_s; a.maskP = maskp; a.outF = out;
    a.M = T_; a.N = D_; a.K = HID_; a.ldOut = D_; a.epi = 3;
    gemm_bt<<<dim3(D_ / 128, T_ / 128, 1), 256, 0, stream>>>(a);
    a.gateP = nullptr; a.maskP = nullptr; a.outF = nullptr;

    // ---------- phase 2: routed experts in batches of <=3 ----------
    const int bstart[3] = {0, 3, 6};
    const int bcnt[3]   = {3, 3, 1};
    for (int b = 0; b < 3; b++) {
        const int eb = bstart[b], Bb = bcnt[b];
        gather_cond_kernel<<<Bb * CAP_ / 4, 256, 0, stream>>>(
            cond_bf, bin_idx + (size_t)eb * CAP_, cond_gb);

        convT_kernel<<<dim3(96, 8, Bb), 256, 0, stream>>>(
            Wada_e + (size_t)eb * DC_ * 3072, wt_b, DC_, 3072,
            (long)DC_ * 3072, (long)DC_ * 3072);
        a.A = cond_gb; a.BT = wt_b; a.bias = bada_e + (size_t)eb * 3072;
        a.out0 = shift_gb; a.out1 = scale_gb;
        a.out2 = gate_g + (size_t)eb * CAP_ * 1024;
        a.M = CAP_; a.N = 3072; a.K = DC_; a.ldOut = 1024;
        a.sA_e = (long)CAP_ * DC_; a.sBT_e = (long)3072 * DC_;
        a.sBias_e = 3072; a.sOut_e = (long)CAP_ * 1024;
        a.n_e = d_ne + eb; a.epi = 0;
        gemm_bt<<<dim3(24, CAP_ / 128, Bb), 256, 0, stream>>>(a);

        modulate_g_kernel<<<Bb * CAP_, 256, 0, stream>>>(
            lnb, shift_gb, scale_gb, bin_idx + (size_t)eb * CAP_, hmod_gb);

        convT_kernel<<<dim3(128, 32, Bb), 256, 0, stream>>>(
            W1_e + (size_t)eb * D_ * HID_, wt_b, D_, HID_,
            (long)D_ * HID_, (long)D_ * HID_);
        a.A = hmod_gb; a.BT = wt_b; a.bias = b1_e + (size_t)eb * HID_; a.out0 = t1_gb;
        a.M = CAP_; a.N = HID_; a.K = D_; a.ldOut = HID_;
        a.sA_e = (long)CAP_ * D_; a.sBT_e = (long)HID_ * D_;
        a.sBias_e = HID_; a.sOut_e = (long)CAP_ * HID_;
        a.epi = 1;
        gemm_bt<<<dim3(HID_ / 128, CAP_ / 128, Bb), 256, 0, stream>>>(a);

        convT_kernel<<<dim3(32, 128, Bb), 256, 0, stream>>>(
            W2_e + (size_t)eb * HID_ * D_, wt_b, HID_, D_,
            (long)HID_ * D_, (long)HID_ * D_);
        a.A = t1_gb; a.BT = wt_b; a.bias = b2_e + (size_t)eb * D_;
        a.out0 = y_g + (size_t)eb * CAP_ * 1024;
        a.M = CAP_; a.N = D_; a.K = HID_; a.ldOut = D_;
        a.sA_e = (long)CAP_ * HID_; a.sBT_e = (long)D_ * HID_;
        a.sBias_e = D_; a.sOut_e = (long)CAP_ * 1024;
        a.epi = 2;
        gemm_bt<<<dim3(D_ / 128, CAP_ / 128, Bb), 256, 0, stream>>>(a);
    }

    // ---------- phase 3: routed combine ----------
    combine_kernel<<<T_, 256, 0, stream>>>(y_g, gate_g, dest_slot, flat_w, maskp, out);
}

// Round 3
// 1210.220 us; speedup vs baseline: 1.1665x; 1.1665x over previous
//
#include <hip/hip_runtime.h>
#include <cstdint>

// ---- problem constants ----
#define B_    4
#define N_    2048
#define D_    1024
#define DC_   256
#define E_    8
#define NE    7          // routed experts addressable by router (E-1)
#define HID_  4096
#define T_    8192       // B*N
#define CAP_  2560       // int(1.25*2*T/E)
#define TP_   16384      // T*TOPK

typedef unsigned short us;

__device__ __forceinline__ float b2f(us h) {
    unsigned u = ((unsigned)h) << 16; float f; __builtin_memcpy(&f, &u, 4); return f;
}
__device__ __forceinline__ us f2b(float f) {
    unsigned u; __builtin_memcpy(&u, &f, 4);
    unsigned r = (u + 0x7fffu + ((u >> 16) & 1u)) >> 16;   // RNE
    return (us)r;
}

using short8 = __attribute__((ext_vector_type(8))) short;
using f32x4  = __attribute__((ext_vector_type(4))) float;

typedef __attribute__((address_space(1))) void GASV;
typedef __attribute__((address_space(3))) void LASV;
__device__ __forceinline__ void gld16(const void* g, void* l) {
    // async global->LDS, 16B/lane, LDS dest = wave-uniform base + lane*16
    __builtin_amdgcn_global_load_lds((GASV*)g, (LASV*)l, 16, 0, 0);
}

// =====================================================================
// 0. sentinel (debug channel: ws too small -> absmax ~12345 next round)
// =====================================================================
__global__ void sentinel_kernel(float* out) { out[0] = 12345.0f; }

// =====================================================================
// 1. Fused router + LayerNorm: one wave per token.
// =====================================================================
__global__ __launch_bounds__(256) void router_ln_kernel(
    const float* __restrict__ x, const float* __restrict__ Wg,
    int* __restrict__ flat_e, float* __restrict__ flat_w, us* __restrict__ lnb)
{
    __shared__ float sWg[D_ * NE];
    for (int i = threadIdx.x; i < D_ * NE; i += 256) sWg[i] = Wg[i];
    __syncthreads();
    const int wave = threadIdx.x >> 6, lane = threadIdx.x & 63;
    const int t = blockIdx.x * 4 + wave;
    const float* xr = x + (size_t)t * D_;

    float v[16];
#pragma unroll
    for (int q = 0; q < 4; q++) {
        float4 f = *(const float4*)(xr + lane * 16 + q * 4);
        v[q*4+0] = f.x; v[q*4+1] = f.y; v[q*4+2] = f.z; v[q*4+3] = f.w;
    }
    float s7[NE] = {0,0,0,0,0,0,0};
    float sum = 0.f, sq = 0.f;
#pragma unroll
    for (int u = 0; u < 16; u++) {
        float xv = v[u]; int d = lane * 16 + u;
        sum += xv; sq += xv * xv;
#pragma unroll
        for (int j = 0; j < NE; j++) s7[j] += xv * sWg[d * NE + j];
    }
#pragma unroll
    for (int off = 32; off; off >>= 1) {
        sum += __shfl_xor(sum, off, 64);
        sq  += __shfl_xor(sq,  off, 64);
#pragma unroll
        for (int j = 0; j < NE; j++) s7[j] += __shfl_xor(s7[j], off, 64);
    }
    const float mu  = sum * (1.f / D_);
    const float var = sq * (1.f / D_) - mu * mu;
    const float rs  = rsqrtf(var + 1e-5f);

    us* lr = lnb + (size_t)t * D_ + lane * 16;
#pragma unroll
    for (int half = 0; half < 2; half++) {
        union { us h[8]; uint4 u4; } p;
#pragma unroll
        for (int u = 0; u < 8; u++) p.h[u] = f2b((v[half*8+u] - mu) * rs);
        *(uint4*)(lr + half * 8) = p.u4;
    }
    if (lane == 0) {
        float m = s7[0];
#pragma unroll
        for (int j = 1; j < NE; j++) m = fmaxf(m, s7[j]);
        float ex[NE];
#pragma unroll
        for (int j = 0; j < NE; j++) ex[j] = __expf(s7[j] - m);
        int i1 = 0;
#pragma unroll
        for (int j = 1; j < NE; j++) if (ex[j] > ex[i1]) i1 = j;
        int i2 = (i1 == 0) ? 1 : 0;
#pragma unroll
        for (int j = 0; j < NE; j++) if (j != i1 && ex[j] > ex[i2]) i2 = j;
        float wA = ex[i1], wB = ex[i2], iw = 1.f / (wA + wB);
        flat_e[t*2]   = i1; flat_e[t*2+1] = i2;
        flat_w[t*2]   = wA * iw; flat_w[t*2+1] = wB * iw;
    }
}

// =====================================================================
// 2. Binning: stable counting sort by expert (single block).
//    Hillis-Steele parallel scan replaces the 256-serial loop.
// =====================================================================
__global__ __launch_bounds__(256) void binning_kernel(
    const int* __restrict__ flat_e, int* __restrict__ bin_idx,
    int* __restrict__ dest_slot, int* __restrict__ n_e)
{
    __shared__ int hist[NE][257];
    __shared__ int sc[2][256];
    const int t = threadIdx.x;
    const int base = t * 64;           // 256 threads * 64 = 16384 pairs
    int cnt[NE] = {0,0,0,0,0,0,0};
    for (int i = 0; i < 64; i++) {
        int fe = flat_e[base + i];
#pragma unroll
        for (int e = 0; e < NE; e++) cnt[e] += (fe == e);
    }
#pragma unroll
    for (int e = 0; e < NE; e++) hist[e][t] = cnt[e];
    __syncthreads();
    for (int e = 0; e < NE; e++) {
        sc[0][t] = hist[e][t];
        __syncthreads();
        int src = 0;
        for (int o = 1; o < 256; o <<= 1) {
            int v = sc[src][t] + ((t >= o) ? sc[src][t - o] : 0);
            sc[src ^ 1][t] = v;
            __syncthreads();
            src ^= 1;
        }
        int incl = sc[src][t];
        hist[e][t] = incl - cnt[e];    // exclusive
        if (t == 255) n_e[e] = incl < CAP_ ? incl : CAP_;
        __syncthreads();
    }
    for (int i = t; i < NE * CAP_; i += 256) bin_idx[i] = -1;
    __syncthreads();
    int ofs[NE];
#pragma unroll
    for (int e = 0; e < NE; e++) ofs[e] = hist[e][t];
    for (int i = 0; i < 64; i++) {
        int idx = base + i;
        int fe = flat_e[idx];
        int r = 0;
#pragma unroll
        for (int e = 0; e < NE; e++) if (fe == e) r = ofs[e]++;
        int slot = (r < CAP_) ? (fe * CAP_ + r) : -1;
        dest_slot[idx] = slot;
        if (slot >= 0) bin_idx[slot] = idx;
    }
}

// =====================================================================
// 3. fp32 -> bf16 elementwise convert (cond)
// =====================================================================
__global__ void cvt_bf16_kernel(const float* __restrict__ in, us* __restrict__ out, long n) {
    long i = ((long)blockIdx.x * 256 + threadIdx.x) * 4;
    if (i >= n) return;
    float4 f = *(const float4*)(in + i);
    union { us h[4]; uint2 u; } p;
    p.h[0] = f2b(f.x); p.h[1] = f2b(f.y); p.h[2] = f2b(f.z); p.h[3] = f2b(f.w);
    *(uint2*)(out + i) = p.u;
}

// =====================================================================
// 4. Weight convert + transpose: W[K,N] fp32 -> WT[N,K] bf16.
//    64x64 tiles, float4 loads, uint4 stores.
// =====================================================================
__global__ __launch_bounds__(256) void convT_kernel(
    const float* __restrict__ W, us* __restrict__ WT, int K, int N, long sW, long sWT)
{
    const float* Wp = W + (size_t)blockIdx.z * sW;
    us* WTp = WT + (size_t)blockIdx.z * sWT;
    __shared__ us tl[64][72];
    const int k0 = blockIdx.y * 64, n0 = blockIdx.x * 64;
    const int lr = threadIdx.x >> 4;      // 0..15 (k row within pass)
    const int lc = threadIdx.x & 15;      // float4 col
#pragma unroll
    for (int p = 0; p < 4; p++) {
        int r = p * 16 + lr;
        float4 f = *(const float4*)(Wp + (size_t)(k0 + r) * N + n0 + lc * 4);
        tl[lc*4+0][r] = f2b(f.x);
        tl[lc*4+1][r] = f2b(f.y);
        tl[lc*4+2][r] = f2b(f.z);
        tl[lc*4+3][r] = f2b(f.w);
    }
    __syncthreads();
    const int nr = threadIdx.x >> 2, kc = (threadIdx.x & 3) * 16;
    union { us h[16]; uint4 u4[2]; } pk;
#pragma unroll
    for (int u = 0; u < 16; u++) pk.h[u] = tl[nr][kc + u];
    us* dst = WTp + (size_t)(n0 + nr) * K + k0 + kc;
    *(uint4*)(dst) = pk.u4[0];
    *(uint4*)(dst + 8) = pk.u4[1];
}

// =====================================================================
// 5. Gather cond rows (bf16) into bin order; invalid slots -> zeros
// =====================================================================
__global__ __launch_bounds__(256) void gather_cond_kernel(
    const us* __restrict__ cond_bf, const int* __restrict__ bin_idx, us* __restrict__ cond_g)
{
    const int row = blockIdx.x * 4 + (threadIdx.x >> 6);
    const int lane = threadIdx.x & 63;
    const int pi = bin_idx[row];
    uint2 val = {0u, 0u};
    if (pi >= 0) val = *(const uint2*)(cond_bf + (size_t)(pi >> 1) * DC_ + lane * 4);
    *(uint2*)(cond_g + (size_t)row * DC_ + lane * 4) = val;
}

// =====================================================================
// 6. GEMM: C[M,N] = A[M,K](bf16) @ BT[N,K]^T + bias.
//    128 x TN tiles, BK=64, XOR-swizzled LDS (bank-conflict-free frag reads),
//    mfma_f32_16x16x32_bf16, global_load_lds(16B). EPI:
//      0 = ada split (shift/scale/gate bf16)   [TN=128]
//      1 = gelu -> bf16                        [TN=128]
//      2 = plain -> bf16                       [TN=64]
//      3 = shared-out: fp32 d_out = val*gate*mask/3  [TN=64]
// =====================================================================
struct GArgs {
    const us* A; const us* BT; const float* bias;
    us* out0; us* out1; us* out2;
    const us* gateP; const float* maskP; float* outF;
    int M, N, K, ldOut;
    long sA_e, sBT_e, sBias_e, sOut_e;
    const int* n_e;
};

template<int TN, int EPI>
__global__ __launch_bounds__(256) void gemm_bt(GArgs g) {
    const int e = blockIdx.z;
    int rows = g.M;
    if (g.n_e) { int ne = g.n_e[e]; if (ne < rows) rows = ne; }
    const int mbase = blockIdx.y * 128;
    if (mbase >= rows) return;                 // block-uniform early exit
    const int nbase = blockIdx.x * TN;
    const us* Ap = g.A  + (size_t)e * g.sA_e;
    const us* BTp = g.BT + (size_t)e * g.sBT_e;
    const int K = g.K;

    constexpr int MI = (TN == 128) ? 4 : 2;    // i-range (wave m-tiles of 16)
    __shared__ __align__(16) us sA[128 * 64];
    __shared__ __align__(16) us sB[TN * 64];

    const int tid = threadIdx.x;
    const int wave = tid >> 6, lane = tid & 63;
    const int wm = (TN == 128) ? (wave >> 1) : wave;
    const int wn = (TN == 128) ? (wave & 1) : 0;
    const int lrow = lane & 15, lq = lane >> 4;
    // staging lane decomposition: 8 rows x 8 chunks per gld16 group
    const int rl = lane >> 3;                  // row within 8-row group
    const int cs = (lane & 7) ^ rl;            // fetch chunk = slot ^ (row&7)

    f32x4 acc[MI][4];
#pragma unroll
    for (int i = 0; i < MI; i++)
#pragma unroll
        for (int j = 0; j < 4; j++) acc[i][j] = (f32x4)0.0f;

    for (int k0 = 0; k0 < K; k0 += 64) {
#pragma unroll
        for (int q = 0; q < 4; q++) {          // A: 128 rows, wave covers 32
            int row = wave * 32 + q * 8 + rl;
            gld16(Ap + (size_t)(mbase + row) * K + k0 + cs * 8, &sA[(wave * 32 + q * 8) * 64]);
        }
#pragma unroll
        for (int q = 0; q < TN / 32; q++) {    // B: TN rows, wave covers TN/4
            int row = wave * (TN / 4) + q * 8 + rl;
            gld16(BTp + (size_t)(nbase + row) * K + k0 + cs * 8, &sB[(wave * (TN / 4) + q * 8) * 64]);
        }
        __syncthreads();
#pragma unroll
        for (int step = 0; step < 2; step++) {
            short8 af[MI], bf[4];
#pragma unroll
            for (int i = 0; i < MI; i++) {
                int r = wm * (MI * 16) + i * 16 + lrow;
                int slot = (step * 4 + lq) ^ (r & 7);
                af[i] = *(const short8*)&sA[r * 64 + slot * 8];
            }
#pragma unroll
            for (int j = 0; j < 4; j++) {
                int r = wn * 64 + j * 16 + lrow;
                int slot = (step * 4 + lq) ^ (r & 7);
                bf[j] = *(const short8*)&sB[r * 64 + slot * 8];
            }
#pragma unroll
            for (int i = 0; i < MI; i++)
#pragma unroll
                for (int j = 0; j < 4; j++)
                    acc[i][j] = __builtin_amdgcn_mfma_f32_16x16x32_bf16(af[i], bf[j], acc[i][j], 0, 0, 0);
        }
        __syncthreads();
    }

    const float* bias = g.bias + (size_t)e * g.sBias_e;
    float bv[4];
#pragma unroll
    for (int j = 0; j < 4; j++) bv[j] = bias[nbase + wn * 64 + j * 16 + lrow];

    if constexpr (EPI == 0) {
        const int seg = nbase >> 10;           // 128-tile never straddles 1024
        us* ob = (seg == 0) ? g.out0 : (seg == 1) ? g.out1 : g.out2;
        ob += (size_t)e * g.sOut_e;
        const int coll = nbase - (seg << 10) + wn * 64 + lrow;
#pragma unroll
        for (int i = 0; i < MI; i++)
#pragma unroll
            for (int r = 0; r < 4; r++) {
                int row = mbase + wm * (MI * 16) + i * 16 + lq * 4 + r;
#pragma unroll
                for (int j = 0; j < 4; j++)
                    ob[(size_t)row * 1024 + coll + j * 16] = f2b(acc[i][j][r] + bv[j]);
            }
    } else if constexpr (EPI == 1) {
        us* ob = g.out0 + (size_t)e * g.sOut_e;
#pragma unroll
        for (int i = 0; i < MI; i++)
#pragma unroll
            for (int r = 0; r < 4; r++) {
                int row = mbase + wm * (MI * 16) + i * 16 + lq * 4 + r;
#pragma unroll
                for (int j = 0; j < 4; j++) {
                    float v = acc[i][j][r] + bv[j];
                    float u = 0.7978845608028654f * (v + 0.044715f * v * v * v);
                    float exu = __expf(2.f * u);
                    float th = 1.f - 2.f / (exu + 1.f);
                    ob[(size_t)row * g.ldOut + nbase + wn * 64 + j * 16 + lrow] = f2b(0.5f * v * (1.f + th));
                }
            }
    } else if constexpr (EPI == 2) {
        us* ob = g.out0 + (size_t)e * g.sOut_e;
#pragma unroll
        for (int i = 0; i < MI; i++)
#pragma unroll
            for (int r = 0; r < 4; r++) {
                int row = mbase + wm * (MI * 16) + i * 16 + lq * 4 + r;
#pragma unroll
                for (int j = 0; j < 4; j++)
                    ob[(size_t)row * g.ldOut + nbase + wn * 64 + j * 16 + lrow] = f2b(acc[i][j][r] + bv[j]);
            }
    } else {
        // EPI 3: fused shared-expert output. out = val * gate * mask / 3 (fp32)
        float* ob = g.outF;
#pragma unroll
        for (int i = 0; i < MI; i++)
#pragma unroll
            for (int r = 0; r < 4; r++) {
                int row = mbase + wm * (MI * 16) + i * 16 + lq * 4 + r;
                float mrow = g.maskP[row] * (1.f / 3.f);
#pragma unroll
                for (int j = 0; j < 4; j++) {
                    int col = nbase + wn * 64 + j * 16 + lrow;
                    float v = acc[i][j][r] + bv[j];
                    ob[(size_t)row * 1024 + col] = v * b2f(g.gateP[(size_t)row * 1024 + col]) * mrow;
                }
            }
    }
}

// =====================================================================
// 7. Modulation: hmod = ln*(1+scale)+shift  (bf16 in/out)
// =====================================================================
__global__ void modulate_s_kernel(const us* __restrict__ lnb, const us* __restrict__ shift,
                                  const us* __restrict__ scale, us* __restrict__ hmod)
{
    size_t i = ((size_t)blockIdx.x * 256 + threadIdx.x) * 4;
    uint2 l  = *(const uint2*)(lnb + i);
    uint2 sh = *(const uint2*)(shift + i);
    uint2 sc = *(const uint2*)(scale + i);
    const us* lp = (const us*)&l; const us* shp = (const us*)&sh; const us* scp = (const us*)&sc;
    union { us h[4]; uint2 u; } o;
#pragma unroll
    for (int u = 0; u < 4; u++)
        o.h[u] = f2b(b2f(lp[u]) * (1.f + b2f(scp[u])) + b2f(shp[u]));
    *(uint2*)(hmod + i) = o.u;
}

__global__ void modulate_g_kernel(const us* __restrict__ lnb, const us* __restrict__ shift_g,
                                  const us* __restrict__ scale_g, const int* __restrict__ bin_idx,
                                  us* __restrict__ hmod_g)
{
    const int slot = blockIdx.x;
    const int d = threadIdx.x * 4;
    const int pi = bin_idx[slot];
    float lv[4] = {0.f, 0.f, 0.f, 0.f};
    if (pi >= 0) {
        uint2 l = *(const uint2*)(lnb + (size_t)(pi >> 1) * D_ + d);
        const us* lp = (const us*)&l;
#pragma unroll
        for (int u = 0; u < 4; u++) lv[u] = b2f(lp[u]);
    }
    const size_t off = (size_t)slot * 1024 + d;
    uint2 sh = *(const uint2*)(shift_g + off);
    uint2 sc = *(const uint2*)(scale_g + off);
    const us* shp = (const us*)&sh; const us* scp = (const us*)&sc;
    union { us h[4]; uint2 u; } o;
#pragma unroll
    for (int u = 0; u < 4; u++)
        o.h[u] = f2b(lv[u] * (1.f + b2f(scp[u])) + b2f(shp[u]));
    *(uint2*)(hmod_g + off) = o.u;
}

// =====================================================================
// 8. Combine (routed add): out[t] += mask*2/3*(w0*g0*y0 + w1*g1*y1)
// =====================================================================
__global__ void combine_kernel(const us* __restrict__ y_g, const us* __restrict__ gate_g,
                               const int* __restrict__ dest_slot, const float* __restrict__ flat_w,
                               const float* __restrict__ maskp, float* __restrict__ out)
{
    const int t = blockIdx.x;
    const int d = threadIdx.x * 4;
    const size_t o = (size_t)t * D_ + d;
    float acc[4] = {0.f, 0.f, 0.f, 0.f};
    const int s0 = dest_slot[2*t], s1 = dest_slot[2*t+1];
    const float w0 = flat_w[2*t] * (2.f / 3.f), w1 = flat_w[2*t+1] * (2.f / 3.f);
    if (s0 >= 0) {
        uint2 yg = *(const uint2*)(y_g + (size_t)s0 * D_ + d);
        uint2 gg = *(const uint2*)(gate_g + (size_t)s0 * D_ + d);
        const us* yp = (const us*)&yg; const us* gp = (const us*)&gg;
#pragma unroll
        for (int u = 0; u < 4; u++) acc[u] += w0 * b2f(gp[u]) * b2f(yp[u]);
    }
    if (s1 >= 0) {
        uint2 yg = *(const uint2*)(y_g + (size_t)s1 * D_ + d);
        uint2 gg = *(const uint2*)(gate_g + (size_t)s1 * D_ + d);
        const us* yp = (const us*)&yg; const us* gp = (const us*)&gg;
#pragma unroll
        for (int u = 0; u < 4; u++) acc[u] += w1 * b2f(gp[u]) * b2f(yp[u]);
    }
    const float mk = maskp[t];
    float4 cur = *(float4*)(out + o);
    cur.x += acc[0] * mk; cur.y += acc[1] * mk;
    cur.z += acc[2] * mk; cur.w += acc[3] * mk;
    *(float4*)(out + o) = cur;
}

// =====================================================================
extern "C" void kernel_launch(void* const* d_in, const int* in_sizes, int n_in,
                              void* d_out, int out_size, void* d_ws, size_t ws_size,
                              hipStream_t stream)
{
    const float* x      = (const float*)d_in[0];
    const float* cond   = (const float*)d_in[1];
    const float* maskp  = (const float*)d_in[2];
    const float* Wg     = (const float*)d_in[3];
    const float* Wada_s = (const float*)d_in[4];
    const float* bada_s = (const float*)d_in[5];
    const float* W1_s   = (const float*)d_in[6];
    const float* b1_s   = (const float*)d_in[7];
    const float* W2_s   = (const float*)d_in[8];
    const float* b2_s   = (const float*)d_in[9];
    const float* Wada_e = (const float*)d_in[10];
    const float* bada_e = (const float*)d_in[11];
    const float* W1_e   = (const float*)d_in[12];
    const float* b1_e   = (const float*)d_in[13];
    const float* W2_e   = (const float*)d_in[14];
    const float* b2_e   = (const float*)d_in[15];
    (void)in_sizes; (void)n_in; (void)out_size;
    float* out = (float*)d_out;

    // ---------- fixed (persistent) allocations ----------
    char* p = (char*)d_ws;
    size_t off = 0;
    auto carve = [&](size_t bytes) -> void* {
        void* r = p + off; off = (off + bytes + 255) & ~(size_t)255; return r;
    };
    int*   flat_e   = (int*)carve((size_t)TP_ * 4);
    float* flat_w   = (float*)carve((size_t)TP_ * 4);
    int*   bin_idx  = (int*)carve((size_t)NE * CAP_ * 4);
    int*   dest_slot= (int*)carve((size_t)TP_ * 4);
    int*   d_ne     = (int*)carve(256);
    us*    cond_bf  = (us*)carve((size_t)T_ * DC_ * 2);          //  4.2 MB
    us*    lnb      = (us*)carve((size_t)T_ * D_ * 2);           // 16.8 MB
    us*    gate_s   = (us*)carve((size_t)T_ * D_ * 2);           // 16.8 MB
    us*    gate_g   = (us*)carve((size_t)NE * CAP_ * D_ * 2);    // 36.7 MB
    us*    y_g      = (us*)carve((size_t)NE * CAP_ * D_ * 2);    // 36.7 MB

    // ---------- scratch arena (lifetimes disjoint across phases) ----------
    char* A = p + off;
    const size_t ARENA_SZ = 103809024;   // max(phase1 92.3MB, phase2 103.8MB)
    // phase 1 (shared expert):
    us* hmod_s  = (us*)(A);                           // 16,777,216
    us* wt_s    = (us*)(A + 16777216);                //  8,388,608 (WadaT/W1T/W2T seq.)
    us* t1_s    = (us*)(A + 25165824);                // 67,108,864
    us* shift_s = (us*)(A + 25165824);                // aliases t1_s (dead before t1 write)
    us* scale_s = (us*)(A + 41943040);
    // phase 2 (routed, batches of <=3 experts):
    us* hmod_gb = (us*)(A);                           // 15,728,640
    us* wt_b    = (us*)(A + 15728640);                // 25,165,824 (WadaT/W1T/W2T seq.)
    us* t1_gb   = (us*)(A + 40894464);                // 62,914,560
    us* shift_gb= (us*)(A + 40894464);                // aliases t1_gb (dead before write)
    us* scale_gb= (us*)(A + 40894464 + 15728640);
    us* cond_gb = (us*)(A + 40894464 + 31457280);

    if (off + ARENA_SZ > ws_size) {                   // debug sentinel
        sentinel_kernel<<<1, 1, 0, stream>>>(out);
        return;
    }

    // ---------- phase 0: router + LN + binning + cond cast ----------
    router_ln_kernel<<<T_ / 4, 256, 0, stream>>>(x, Wg, flat_e, flat_w, lnb);
    binning_kernel<<<1, 256, 0, stream>>>(flat_e, bin_idx, dest_slot, d_ne);
    cvt_bf16_kernel<<<(T_ * DC_) / 1024, 256, 0, stream>>>(cond, cond_bf, (long)T_ * DC_);

    GArgs a;
    a.gateP = nullptr; a.maskP = nullptr; a.outF = nullptr;

    // ---------- phase 1: shared expert ----------
    convT_kernel<<<dim3(48, 4, 1), 256, 0, stream>>>(Wada_s, wt_s, DC_, 3072, 0, 0);
    a.A = cond_bf; a.BT = wt_s; a.bias = bada_s;
    a.out0 = shift_s; a.out1 = scale_s; a.out2 = gate_s;
    a.M = T_; a.N = 3072; a.K = DC_; a.ldOut = 1024;
    a.sA_e = 0; a.sBT_e = 0; a.sBias_e = 0; a.sOut_e = 0;
    a.n_e = nullptr;
    gemm_bt<128, 0><<<dim3(24, T_ / 128, 1), 256, 0, stream>>>(a);

    modulate_s_kernel<<<(T_ * D_) / 1024, 256, 0, stream>>>(lnb, shift_s, scale_s, hmod_s);

    convT_kernel<<<dim3(64, 16, 1), 256, 0, stream>>>(W1_s, wt_s, D_, HID_, 0, 0);
    a.A = hmod_s; a.BT = wt_s; a.bias = b1_s; a.out0 = t1_s;
    a.M = T_; a.N = HID_; a.K = D_; a.ldOut = HID_;
    gemm_bt<128, 1><<<dim3(HID_ / 128, T_ / 128, 1), 256, 0, stream>>>(a);

    convT_kernel<<<dim3(16, 64, 1), 256, 0, stream>>>(W2_s, wt_s, HID_, D_, 0, 0);
    a.A = t1_s; a.BT = wt_s; a.bias = b2_s; a.out0 = nullptr;
    a.gateP = gate_s; a.maskP = maskp; a.outF = out;
    a.M = T_; a.N = D_; a.K = HID_; a.ldOut = D_;
    gemm_bt<64, 3><<<dim3(D_ / 64, T_ / 128, 1), 256, 0, stream>>>(a);
    a.gateP = nullptr; a.maskP = nullptr; a.outF = nullptr;

    // ---------- phase 2: routed experts in batches of <=3 ----------
    const int bstart[3] = {0, 3, 6};
    const int bcnt[3]   = {3, 3, 1};
    for (int b = 0; b < 3; b++) {
        const int eb = bstart[b], Bb = bcnt[b];
        gather_cond_kernel<<<Bb * CAP_ / 4, 256, 0, stream>>>(
            cond_bf, bin_idx + (size_t)eb * CAP_, cond_gb);

        convT_kernel<<<dim3(48, 4, Bb), 256, 0, stream>>>(
            Wada_e + (size_t)eb * DC_ * 3072, wt_b, DC_, 3072,
            (long)DC_ * 3072, (long)DC_ * 3072);
        a.A = cond_gb; a.BT = wt_b; a.bias = bada_e + (size_t)eb * 3072;
        a.out0 = shift_gb; a.out1 = scale_gb;
        a.out2 = gate_g + (size_t)eb * CAP_ * 1024;
        a.M = CAP_; a.N = 3072; a.K = DC_; a.ldOut = 1024;
        a.sA_e = (long)CAP_ * DC_; a.sBT_e = (long)3072 * DC_;
        a.sBias_e = 3072; a.sOut_e = (long)CAP_ * 1024;
        a.n_e = d_ne + eb;
        gemm_bt<128, 0><<<dim3(24, CAP_ / 128, Bb), 256, 0, stream>>>(a);

        modulate_g_kernel<<<Bb * CAP_, 256, 0, stream>>>(
            lnb, shift_gb, scale_gb, bin_idx + (size_t)eb * CAP_, hmod_gb);

        convT_kernel<<<dim3(64, 16, Bb), 256, 0, stream>>>(
            W1_e + (size_t)eb * D_ * HID_, wt_b, D_, HID_,
            (long)D_ * HID_, (long)D_ * HID_);
        a.A = hmod_gb; a.BT = wt_b; a.bias = b1_e + (size_t)eb * HID_; a.out0 = t1_gb;
        a.M = CAP_; a.N = HID_; a.K = D_; a.ldOut = HID_;
        a.sA_e = (long)CAP_ * D_; a.sBT_e = (long)HID_ * D_;
        a.sBias_e = HID_; a.sOut_e = (long)CAP_ * HID_;
        gemm_bt<128, 1><<<dim3(HID_ / 128, CAP_ / 128, Bb), 256, 0, stream>>>(a);

        convT_kernel<<<dim3(16, 64, Bb), 256, 0, stream>>>(
            W2_e + (size_t)eb * HID_ * D_, wt_b, HID_, D_,
            (long)HID_ * D_, (long)HID_ * D_);
        a.A = t1_gb; a.BT = wt_b; a.bias = b2_e + (size_t)eb * D_;
        a.out0 = y_g + (size_t)eb * CAP_ * 1024;
        a.M = CAP_; a.N = D_; a.K = HID_; a.ldOut = D_;
        a.sA_e = (long)CAP_ * HID_; a.sBT_e = (long)D_ * HID_;
        a.sBias_e = D_; a.sOut_e = (long)CAP_ * 1024;
        gemm_bt<64, 2><<<dim3(D_ / 64, CAP_ / 128, Bb), 256, 0, stream>>>(a);
    }

    // ---------- phase 3: routed combine ----------
    combine_kernel<<<T_, 256, 0, stream>>>(y_g, gate_g, dest_slot, flat_w, maskp, out);
}